// Round 4
// baseline (266.078 us; speedup 1.0000x reference)
//
#include <hip/hip_runtime.h>
#include <hip/hip_bf16.h>

#define BB 8
#define NN 2048
#define FIN 128
#define FO 64
#define ALPHA 0.2f

typedef __attribute__((ext_vector_type(8))) short bf16x8;
typedef __attribute__((ext_vector_type(4))) float f32x4;
typedef __attribute__((ext_vector_type(4))) int i32x4;

__device__ inline short f2bf(float x) {
    unsigned u = __float_as_uint(x);
    u += 0x7fffu + ((u >> 16) & 1u);   // RNE, sign-agnostic, no NaN inputs here
    return (short)(u >> 16);
}

// ---------------- Kernel A: Wh = h@W; whF in MFMA B-fragment layout ----------
// whF[b][jc][ot][lane][8] shorts: lane L holds Wh[b][j=jc*32+(L>>4)*8+jj][o=ot*16+(L&15)]
// h rows are wave-uniform -> scalar (K$) loads; no LDS, no barrier.
// e2 maxes: ONE non-atomic float store per wave into e2p[b][0..255].
__global__ __launch_bounds__(256) void wh_kernel(
    const float* __restrict__ h, const float* __restrict__ W,
    const float* __restrict__ a, float* __restrict__ e1, float* __restrict__ e2,
    float* __restrict__ e2p, short* __restrict__ whF)
{
    const int t  = threadIdx.x;
    const int o  = t & 63;
    const int wv = t >> 6;                     // rows wv*8 .. wv*8+7
    const int r0 = blockIdx.x * 32;            // 32 rows per block (same batch)
    const float* __restrict__ hrow =
        h + (size_t)(r0 + __builtin_amdgcn_readfirstlane(wv) * 8) * FIN;

    float acc[8];
#pragma unroll
    for (int rr = 0; rr < 8; rr++) acc[rr] = 0.f;

    for (int f = 0; f < FIN; f += 4) {
        const float w0 = W[(f + 0) * FO + o];
        const float w1 = W[(f + 1) * FO + o];
        const float w2 = W[(f + 2) * FO + o];
        const float w3 = W[(f + 3) * FO + o];
#pragma unroll
        for (int rr = 0; rr < 8; rr++) {
            const float4 hv = *(const float4*)(hrow + rr * FIN + f);  // uniform -> SGPR
            acc[rr] = fmaf(hv.x, w0, acc[rr]);
            acc[rr] = fmaf(hv.y, w1, acc[rr]);
            acc[rr] = fmaf(hv.z, w2, acc[rr]);
            acc[rr] = fmaf(hv.w, w3, acc[rr]);
        }
    }

    // fragment-layout store: one contiguous 16B per lane
    const int b   = r0 / NN;
    const int ib0 = r0 - b * NN;
    const int ibb = ib0 + wv * 8;
    const int jc  = ibb >> 5;
    const int qq  = (ibb >> 3) & 3;
    const int ot  = o >> 4, mm = o & 15;
    const int L   = mm + qq * 16;
    bf16x8 frag;
#pragma unroll
    for (int rr = 0; rr < 8; rr++) frag[rr] = f2bf(acc[rr]);
    *(bf16x8*)(whF + ((((size_t)(b * 64 + jc) * 4 + ot) * 64 + L) * 8)) = frag;

    const float a1 = a[o], a2 = a[FO + o];
    float vmax = -3.0e38f;
#pragma unroll
    for (int rr = 0; rr < 8; rr++) {
        float v1 = acc[rr] * a1, v2 = acc[rr] * a2;
#pragma unroll
        for (int msk = 32; msk >= 1; msk >>= 1) {
            v1 += __shfl_xor(v1, msk, 64);
            v2 += __shfl_xor(v2, msk, 64);
        }
        vmax = fmaxf(vmax, v2);
        if (o == 0) { e1[r0 + wv * 8 + rr] = v1; e2[r0 + wv * 8 + rr] = v2; }
    }
    if (o == 0) e2p[b * 256 + (ib0 >> 5) * 4 + wv] = vmax;
}

// ---------------- Kernel B: fused attention, barrier-free main loop ----------
// adj has ZERO reuse (each row read once by one block) -> no LDS staging.
// Each lane reads its own adj quarters directly from global: per (a0,a1) pair
// the wave covers 16 rows x 128 contiguous B/row (same 64B-transaction count
// as the staged path, minus LDS round-trip / dbuf / barriers / vmcnt games).
// Distance-1 software prefetch + 16 waves/CU TLP covers HBM latency
// (16 waves x 2KB / ~900cy = 36 B/cy/CU > 25 B/cy needed for 6.3 TB/s).
// LDS is only the one-shot epilogue combine (16.7 KB).
struct SMemC { float comb[4][16][64]; float lsum[4][16]; float red4[4]; };

#define STEP(K, A0, A1) do {                                                  \
    const int sb = ((K) >> 1) * 256 + ((K) & 1) * 32;                         \
    const short* bfp = whFb + (size_t)((sb + w * 64) >> 5) * 2048 + lane * 8; \
    bf16x8 b0 = *(const bf16x8*)(bfp);                                        \
    bf16x8 b1 = *(const bf16x8*)(bfp + 512);                                  \
    bf16x8 b2 = *(const bf16x8*)(bfp + 1024);                                 \
    bf16x8 b3 = *(const bf16x8*)(bfp + 1536);                                 \
    const float* e2w = e2b + sb + w * 64 + q * 8;                             \
    f32x4 ev0 = *(const f32x4*)(e2w);                                         \
    f32x4 ev1 = *(const f32x4*)(e2w + 4);                                     \
    bf16x8 af;                                                                \
    _Pragma("unroll")                                                         \
    for (int jj = 0; jj < 8; jj++) {                                          \
        const int   av  = (jj < 4) ? (A0)[jj] : (A1)[jj - 4];                 \
        const float e2j = (jj < 4) ? ev0[jj]  : ev1[jj - 4];                  \
        float e = e1v + e2j;                                                  \
        e = e > 0.f ? e : ALPHA * e;                                          \
        const float pe = (av > 0) ? __expf(e - mi) : 0.f;                     \
        lsum += pe;                                                           \
        af[jj] = f2bf(pe);                                                    \
    }                                                                         \
    acc0 = __builtin_amdgcn_mfma_f32_16x16x32_bf16(af, b0, acc0, 0, 0, 0);    \
    acc1 = __builtin_amdgcn_mfma_f32_16x16x32_bf16(af, b1, acc1, 0, 0, 0);    \
    acc2 = __builtin_amdgcn_mfma_f32_16x16x32_bf16(af, b2, acc2, 0, 0, 0);    \
    acc3 = __builtin_amdgcn_mfma_f32_16x16x32_bf16(af, b3, acc3, 0, 0, 0);    \
} while (0)

__global__ __launch_bounds__(256, 4) void attn_kernel(
    const int* __restrict__ adj, const float* __restrict__ e1,
    const float* __restrict__ e2, const float* __restrict__ e2p,
    const short* __restrict__ whF, float* __restrict__ out)
{
    __shared__ SMemC sm;
    const int t = threadIdx.x, w = t >> 6, lane = t & 63;
    const int m = lane & 15, q = lane >> 4;
    const int blk = blockIdx.x;
    const int b  = blk >> 7;
    const int i0 = (blk & 127) * 16;
    const int i  = i0 + m;

    // ---- batch e2max from per-wave partials (256 floats, L2-resident) ----
    float pv = e2p[b * 256 + t];
    const float e1v = e1[b * NN + i];
#pragma unroll
    for (int k = 32; k >= 1; k >>= 1) pv = fmaxf(pv, __shfl_xor(pv, k, 64));
    if (lane == 0) sm.red4[w] = pv;
    __syncthreads();
    const float e2mx = fmaxf(fmaxf(sm.red4[0], sm.red4[1]),
                             fmaxf(sm.red4[2], sm.red4[3]));

    float mi = e1v + e2mx;
    mi = mi > 0.f ? mi : ALPHA * mi;           // safe per-row max bound (leakyrelu monotone)

    const short* whFb = whF + (size_t)b * (64 * 4 * 64 * 8);
    // lane's adj base: row i, col = w*64 + q*8 (+ per-step slab offset)
    const int* arow = adj + ((size_t)(b * NN + i)) * NN + w * 64 + q * 8;
    const float* e2b = e2 + b * NN;

    f32x4 acc0 = {0.f,0.f,0.f,0.f}, acc1 = acc0, acc2 = acc0, acc3 = acc0;
    float lsum = 0.f;

    // 16 steps of 32 j-columns each (this wave's quarter of j-space),
    // explicit distance-1 prefetch, no barriers, no LDS in the loop.
    i32x4 ca0 = *(const i32x4*)(arow);
    i32x4 ca1 = *(const i32x4*)(arow + 4);
#pragma unroll
    for (int k = 0; k < 15; k++) {
        const int nsb = ((k + 1) >> 1) * 256 + ((k + 1) & 1) * 32;
        i32x4 na0 = *(const i32x4*)(arow + nsb);
        i32x4 na1 = *(const i32x4*)(arow + nsb + 4);
        STEP(k, ca0, ca1);
        ca0 = na0; ca1 = na1;
    }
    STEP(15, ca0, ca1);

    // cross-wave combine in LDS (each wave saw a disjoint j quarter)
    lsum += __shfl_xor(lsum, 16, 64);
    lsum += __shfl_xor(lsum, 32, 64);
    if (q == 0) sm.lsum[w][m] = lsum;
#pragma unroll
    for (int ot = 0; ot < 4; ot++) {
        f32x4 av = (ot == 0) ? acc0 : (ot == 1) ? acc1 : (ot == 2) ? acc2 : acc3;
#pragma unroll
        for (int reg = 0; reg < 4; reg++)
            sm.comb[w][q * 4 + reg][ot * 16 + m] = av[reg];
    }
    __syncthreads();

    const int row = t >> 4, c0 = (t & 15) * 4;
    f32x4 sum = *(const f32x4*)&sm.comb[0][row][c0];
#pragma unroll
    for (int ww = 1; ww < 4; ww++) {
        f32x4 sv = *(const f32x4*)&sm.comb[ww][row][c0];
        sum.x += sv.x; sum.y += sv.y; sum.z += sv.z; sum.w += sv.w;
    }
    float l = sm.lsum[0][row] + sm.lsum[1][row] + sm.lsum[2][row] + sm.lsum[3][row];
    l = fmaxf(l, 1e-30f);
    const float rl = 1.f / l;
    float vr[4] = { sum.x * rl, sum.y * rl, sum.z * rl, sum.w * rl };
    f32x4 res;
#pragma unroll
    for (int kk = 0; kk < 4; kk++)
        res[kk] = vr[kk] > 0.f ? vr[kk] : (__expf(vr[kk]) - 1.f);
    *(f32x4*)&out[((size_t)(b * NN + i0 + row)) * FO + c0] = res;
}

extern "C" void kernel_launch(void* const* d_in, const int* in_sizes, int n_in,
                              void* d_out, int out_size, void* d_ws, size_t ws_size,
                              hipStream_t stream) {
    const float* h   = (const float*)d_in[0];
    const int*   adj = (const int*)d_in[1];
    const float* W   = (const float*)d_in[2];
    const float* a   = (const float*)d_in[3];
    float* out = (float*)d_out;

    char* ws = (char*)d_ws;
    short* whF = (short*)ws;                                   // 2 MB
    size_t off = (size_t)BB * 64 * 4 * 64 * 8 * sizeof(short);
    float* e1  = (float*)(ws + off);  off += (size_t)BB * NN * 4;
    float* e2  = (float*)(ws + off);  off += (size_t)BB * NN * 4;
    float* e2p = (float*)(ws + off);                           // 8 x 256 partial maxes

    wh_kernel<<<(BB * NN) / 32, 256, 0, stream>>>(h, W, a, e1, e2, e2p, whF);
    attn_kernel<<<BB * (NN / 16), 256, 0, stream>>>(adj, e1, e2, e2p, whF, out);
}

// Round 5
// 233.553 us; speedup vs baseline: 1.1393x; 1.1393x over previous
//
#include <hip/hip_runtime.h>
#include <hip/hip_bf16.h>

#define BB 8
#define NN 2048
#define FIN 128
#define FO 64
#define ALPHA 0.2f

typedef __attribute__((ext_vector_type(8))) short bf16x8;
typedef __attribute__((ext_vector_type(4))) float f32x4;
typedef __attribute__((ext_vector_type(4))) int i32x4;

__device__ inline short f2bf(float x) {
    unsigned u = __float_as_uint(x);
    u += 0x7fffu + ((u >> 16) & 1u);   // RNE, sign-agnostic, no NaN inputs here
    return (short)(u >> 16);
}

// ---------------- Kernel A: Wh = h@W; whF in MFMA B-fragment layout ----------
// whF[b][jc][ot][lane][8] shorts: lane L holds Wh[b][j=jc*32+(L>>4)*8+jj][o=ot*16+(L&15)]
// h rows are wave-uniform -> scalar (K$) loads; no LDS, no barrier.
// e2 maxes: ONE non-atomic float store per wave into e2p[b][0..255].
__global__ __launch_bounds__(256) void wh_kernel(
    const float* __restrict__ h, const float* __restrict__ W,
    const float* __restrict__ a, float* __restrict__ e1, float* __restrict__ e2,
    float* __restrict__ e2p, short* __restrict__ whF)
{
    const int t  = threadIdx.x;
    const int o  = t & 63;
    const int wv = t >> 6;                     // rows wv*8 .. wv*8+7
    const int r0 = blockIdx.x * 32;            // 32 rows per block (same batch)
    const float* __restrict__ hrow =
        h + (size_t)(r0 + __builtin_amdgcn_readfirstlane(wv) * 8) * FIN;

    float acc[8];
#pragma unroll
    for (int rr = 0; rr < 8; rr++) acc[rr] = 0.f;

    for (int f = 0; f < FIN; f += 4) {
        const float w0 = W[(f + 0) * FO + o];
        const float w1 = W[(f + 1) * FO + o];
        const float w2 = W[(f + 2) * FO + o];
        const float w3 = W[(f + 3) * FO + o];
#pragma unroll
        for (int rr = 0; rr < 8; rr++) {
            const float4 hv = *(const float4*)(hrow + rr * FIN + f);  // uniform -> SGPR
            acc[rr] = fmaf(hv.x, w0, acc[rr]);
            acc[rr] = fmaf(hv.y, w1, acc[rr]);
            acc[rr] = fmaf(hv.z, w2, acc[rr]);
            acc[rr] = fmaf(hv.w, w3, acc[rr]);
        }
    }

    const int b   = r0 / NN;
    const int ib0 = r0 - b * NN;
    const int ibb = ib0 + wv * 8;
    const int jc  = ibb >> 5;
    const int qq  = (ibb >> 3) & 3;
    const int ot  = o >> 4, mm = o & 15;
    const int L   = mm + qq * 16;
    bf16x8 frag;
#pragma unroll
    for (int rr = 0; rr < 8; rr++) frag[rr] = f2bf(acc[rr]);
    *(bf16x8*)(whF + ((((size_t)(b * 64 + jc) * 4 + ot) * 64 + L) * 8)) = frag;

    const float a1 = a[o], a2 = a[FO + o];
    float vmax = -3.0e38f;
#pragma unroll
    for (int rr = 0; rr < 8; rr++) {
        float v1 = acc[rr] * a1, v2 = acc[rr] * a2;
#pragma unroll
        for (int msk = 32; msk >= 1; msk >>= 1) {
            v1 += __shfl_xor(v1, msk, 64);
            v2 += __shfl_xor(v2, msk, 64);
        }
        vmax = fmaxf(vmax, v2);
        if (o == 0) { e1[r0 + wv * 8 + rr] = v1; e2[r0 + wv * 8 + rr] = v2; }
    }
    if (o == 0) e2p[b * 256 + (ib0 >> 5) * 4 + wv] = vmax;
}

// ---------------- Kernel B: fused attention, register-pipelined global loads -
// R4 post-mortem: distance-1 adj prefetch + in-order vmcnt retirement exposed
// ~900cy HBM latency EVERY step (2.4 KB/CU in flight measured).  Fix: modulo
// schedule.  adj in 4 register slots issued 4 steps ahead; whF/e2 double-
// buffered issued 1 step ahead.  Issue order per step (pinned by mem fences):
//   [wh(k+1),e2(k+1)] | [compute k] | [adj(k+4)]
// so consuming wh(k+1) at step k+1 waits only past its own (L2-hit) loads,
// never draining the young adj prefetches; adj(k) is 4 steps (~>1000cy) old at
// consumption -> retired.  In flight/wave: 8KB adj + 4KB whF; x16 waves/CU
// ~190KB >> 22.5KB Little's-law need.  No barriers, no LDS in the loop.
struct SMemC { float comb[4][16][64]; float lsum[4][16]; float red4[4]; };

#define SB(K) (((K) >> 1) * 256 + ((K) & 1) * 32)

__global__ __launch_bounds__(256, 4) void attn_kernel(
    const int* __restrict__ adj, const float* __restrict__ e1,
    const float* __restrict__ e2, const float* __restrict__ e2p,
    const short* __restrict__ whF, float* __restrict__ out)
{
    __shared__ SMemC sm;
    const int t = threadIdx.x, w = t >> 6, lane = t & 63;
    const int m = lane & 15, q = lane >> 4;
    const int blk = blockIdx.x;
    const int b  = blk >> 7;
    const int i0 = (blk & 127) * 16;
    const int i  = i0 + m;

    // ---- batch e2max from per-wave partials (256 floats, L2-resident) ----
    float pv = e2p[b * 256 + t];
    const float e1v = e1[b * NN + i];
#pragma unroll
    for (int k = 32; k >= 1; k >>= 1) pv = fmaxf(pv, __shfl_xor(pv, k, 64));
    if (lane == 0) sm.red4[w] = pv;
    __syncthreads();
    const float e2mx = fmaxf(fmaxf(sm.red4[0], sm.red4[1]),
                             fmaxf(sm.red4[2], sm.red4[3]));

    float mi = e1v + e2mx;
    mi = mi > 0.f ? mi : ALPHA * mi;           // safe per-row max bound (leakyrelu monotone)

    const short* whFb = whF + (size_t)b * (64 * 4 * 64 * 8);
    const int* arow = adj + ((size_t)(b * NN + i)) * NN + w * 64 + q * 8;
    const float* e2b = e2 + b * NN;

    f32x4 acc0 = {0.f,0.f,0.f,0.f}, acc1 = acc0, acc2 = acc0, acc3 = acc0;
    float lsum = 0.f;

    i32x4 aj0[4], aj1[4];      // adj slots, depth-4 prefetch (static idx post-unroll)
    bf16x8 wb[2][4];           // whF double buffer
    f32x4  eb[2][2];           // e2 double buffer

    // prologue: wh(0), e2(0) first (older in queue than adj -> consuming them
    // never forces adj retirement), then adj(0..3).
    {
        const short* bfp = whFb + (size_t)((SB(0) + w * 64) >> 5) * 2048 + lane * 8;
        wb[0][0] = *(const bf16x8*)(bfp);
        wb[0][1] = *(const bf16x8*)(bfp + 512);
        wb[0][2] = *(const bf16x8*)(bfp + 1024);
        wb[0][3] = *(const bf16x8*)(bfp + 1536);
        const float* ew = e2b + SB(0) + w * 64 + q * 8;
        eb[0][0] = *(const f32x4*)(ew);
        eb[0][1] = *(const f32x4*)(ew + 4);
    }
    asm volatile("" ::: "memory");
#pragma unroll
    for (int k = 0; k < 4; k++) {
        aj0[k] = *(const i32x4*)(arow + SB(k));
        aj1[k] = *(const i32x4*)(arow + SB(k) + 4);
    }
    asm volatile("" ::: "memory");

#pragma unroll
    for (int k = 0; k < 16; k++) {
        // ---- prefetch wh/e2 for k+1 (L2-resident, 1-step lead) ----
        if (k < 15) {
            const int sbn = SB(k + 1);
            const short* bfp = whFb + (size_t)((sbn + w * 64) >> 5) * 2048 + lane * 8;
            wb[(k + 1) & 1][0] = *(const bf16x8*)(bfp);
            wb[(k + 1) & 1][1] = *(const bf16x8*)(bfp + 512);
            wb[(k + 1) & 1][2] = *(const bf16x8*)(bfp + 1024);
            wb[(k + 1) & 1][3] = *(const bf16x8*)(bfp + 1536);
            const float* ew = e2b + sbn + w * 64 + q * 8;
            eb[(k + 1) & 1][0] = *(const f32x4*)(ew);
            eb[(k + 1) & 1][1] = *(const f32x4*)(ew + 4);
        }
        asm volatile("" ::: "memory");   // adj(k+4) must issue AFTER wh(k+1)

        // ---- compute step k (registers only) ----
        {
            bf16x8 af;
#pragma unroll
            for (int jj = 0; jj < 8; jj++) {
                const int   av  = (jj < 4) ? aj0[k & 3][jj] : aj1[k & 3][jj - 4];
                const float e2j = (jj < 4) ? eb[k & 1][0][jj] : eb[k & 1][1][jj - 4];
                float e = e1v + e2j;
                e = e > 0.f ? e : ALPHA * e;
                const float pe = (av > 0) ? __expf(e - mi) : 0.f;
                lsum += pe;
                af[jj] = f2bf(pe);
            }
            acc0 = __builtin_amdgcn_mfma_f32_16x16x32_bf16(af, wb[k & 1][0], acc0, 0, 0, 0);
            acc1 = __builtin_amdgcn_mfma_f32_16x16x32_bf16(af, wb[k & 1][1], acc1, 0, 0, 0);
            acc2 = __builtin_amdgcn_mfma_f32_16x16x32_bf16(af, wb[k & 1][2], acc2, 0, 0, 0);
            acc3 = __builtin_amdgcn_mfma_f32_16x16x32_bf16(af, wb[k & 1][3], acc3, 0, 0, 0);
        }

        // ---- refill adj slot (k&3) with step k+4 (after its last use above) ----
        if (k < 12) {
            aj0[k & 3] = *(const i32x4*)(arow + SB(k + 4));
            aj1[k & 3] = *(const i32x4*)(arow + SB(k + 4) + 4);
        }
        asm volatile("" ::: "memory");   // keep next iter's wh issue after this
    }

    // cross-wave combine in LDS (each wave saw a disjoint j quarter)
    lsum += __shfl_xor(lsum, 16, 64);
    lsum += __shfl_xor(lsum, 32, 64);
    if (q == 0) sm.lsum[w][m] = lsum;
#pragma unroll
    for (int ot = 0; ot < 4; ot++) {
        f32x4 av = (ot == 0) ? acc0 : (ot == 1) ? acc1 : (ot == 2) ? acc2 : acc3;
#pragma unroll
        for (int reg = 0; reg < 4; reg++)
            sm.comb[w][q * 4 + reg][ot * 16 + m] = av[reg];
    }
    __syncthreads();

    const int row = t >> 4, c0 = (t & 15) * 4;
    f32x4 sum = *(const f32x4*)&sm.comb[0][row][c0];
#pragma unroll
    for (int ww = 1; ww < 4; ww++) {
        f32x4 sv = *(const f32x4*)&sm.comb[ww][row][c0];
        sum.x += sv.x; sum.y += sv.y; sum.z += sv.z; sum.w += sv.w;
    }
    float l = sm.lsum[0][row] + sm.lsum[1][row] + sm.lsum[2][row] + sm.lsum[3][row];
    l = fmaxf(l, 1e-30f);
    const float rl = 1.f / l;
    float vr[4] = { sum.x * rl, sum.y * rl, sum.z * rl, sum.w * rl };
    f32x4 res;
#pragma unroll
    for (int kk = 0; kk < 4; kk++)
        res[kk] = vr[kk] > 0.f ? vr[kk] : (__expf(vr[kk]) - 1.f);
    *(f32x4*)&out[((size_t)(b * NN + i0 + row)) * FO + c0] = res;
}

extern "C" void kernel_launch(void* const* d_in, const int* in_sizes, int n_in,
                              void* d_out, int out_size, void* d_ws, size_t ws_size,
                              hipStream_t stream) {
    const float* h   = (const float*)d_in[0];
    const int*   adj = (const int*)d_in[1];
    const float* W   = (const float*)d_in[2];
    const float* a   = (const float*)d_in[3];
    float* out = (float*)d_out;

    char* ws = (char*)d_ws;
    short* whF = (short*)ws;                                   // 2 MB
    size_t off = (size_t)BB * 64 * 4 * 64 * 8 * sizeof(short);
    float* e1  = (float*)(ws + off);  off += (size_t)BB * NN * 4;
    float* e2  = (float*)(ws + off);  off += (size_t)BB * NN * 4;
    float* e2p = (float*)(ws + off);                           // 8 x 256 partial maxes

    wh_kernel<<<(BB * NN) / 32, 256, 0, stream>>>(h, W, a, e1, e2, e2p, whF);
    attn_kernel<<<BB * (NN / 16), 256, 0, stream>>>(adj, e1, e2, e2p, whF, out);
}